// Round 12
// baseline (240.010 us; speedup 1.0000x reference)
//
#include <hip/hip_runtime.h>

#define BB   4
#define NN   256
#define TT   4096
#define DD   128      // SIM_DIM
#define LK   101      // LOOKUP
#define PADK 50
#define OD   128      // OUT_DIM
#define ROWS 164      // 64 + LK - 1 rows of halo'd proj window
#define P16W 68       // f16 band: row stride in u32 units (64 data + 4 pad = 272 B)
#define FS_STR 68     // proj fs row stride (64 t + 4 pad)
#define WB_STR 132    // proj wbuf row stride (128 d + 4 pad)

typedef float vfloat4 __attribute__((ext_vector_type(4)));
typedef unsigned int vuint4 __attribute__((ext_vector_type(4)));
typedef _Float16 half2v __attribute__((ext_vector_type(2)));

__device__ inline float fdot2f(half2v a, half2v b, float c) {
#if __has_builtin(__builtin_amdgcn_fdot2)
  return __builtin_amdgcn_fdot2(a, b, c, false);
#else
  return c + (float)a.x * (float)b.x + (float)a.y * (float)b.y;
#endif
}
__device__ inline unsigned int pk16(float lo, float hi) {
  return __builtin_bit_cast(unsigned int, __builtin_amdgcn_cvt_pkrtz(lo, hi));
}
__device__ inline half2v h2(unsigned int u) {
  return __builtin_bit_cast(half2v, u);
}

// ---------------- kernel 1: one-time weight transposes ----------------
__global__ __launch_bounds__(256) void transpose_w_kernel(
    const float* __restrict__ w_proj, const float* __restrict__ w_fc,
    float* __restrict__ w_t, float* __restrict__ wfc_t) {
  int idx = blockIdx.x * 256 + threadIdx.x;
  int stride = gridDim.x * 256;
  for (int i = idx; i < DD * NN; i += stride) {
    int d = i / NN, n = i - d * NN;
    w_t[n * DD + d] = w_proj[i];
  }
  for (int i = idx; i < OD * LK; i += stride) {
    int o = i / LK, j = i - o * LK;
    wfc_t[j * OD + o] = w_fc[i];
  }
}

// ---------------- kernel 2: spatial mean-pool v3 (= v2, NT flag removed) ----------------
// Single-variable ablation: plain (cached) loads instead of nontemporal.
__global__ __launch_bounds__(256) void pool_kernel(
    const float* __restrict__ x, float* __restrict__ feat) {
  __shared__ float part[512 * 13];   // 26.6 KB
  int tid = threadIdx.x;
  const vfloat4* x4 = (const vfloat4*)x + (size_t)blockIdx.x * 6144;

  vfloat4 v[24];
#pragma unroll
  for (int k = 0; k < 24; ++k)
    v[k] = x4[tid + 256 * k];        // plain load (was __builtin_nontemporal_load)

#pragma unroll
  for (int k = 0; k < 24; ++k) {
    int j = tid + 256 * k;
    int r = j / 12, i = j - r * 12;
    part[r * 13 + i] = (v[k].x + v[k].y) + (v[k].z + v[k].w);
  }
  __syncthreads();

  float* fo = feat + (size_t)blockIdx.x * 512;
#pragma unroll
  for (int q = 0; q < 2; ++q) {
    int o = tid + q * 256;
    const float* pp = part + o * 13;
    float a0 = 0.f, a1 = 0.f;
#pragma unroll
    for (int i = 0; i < 6; ++i) { a0 += pp[i]; a1 += pp[6 + i]; }
    fo[o] = (a0 + a1) * (1.0f / 48.0f);
  }
}

// ---------------- kernel 3: projection + L2 normalize (v3, R8 exact) ----------------
__global__ __launch_bounds__(512, 1) void proj_kernel(
    const float* __restrict__ feat, const float* __restrict__ w_t,
    float* __restrict__ projn) {
  extern __shared__ float smemP[];
  float* fs   = smemP;               // [256 n][68]
  float* wbuf = smemP + NN * FS_STR; // [64 n][132]
  int b = blockIdx.x >> 6;
  int t0 = (blockIdx.x & 63) << 6;
  int tid = threadIdx.x;
  int td = tid & 31, tt = tid >> 5;

  float acc[4][4];
#pragma unroll
  for (int i = 0; i < 4; ++i)
#pragma unroll
    for (int j = 0; j < 4; ++j) acc[i][j] = 0.f;

  for (int c = 0; c < 4; ++c) {
    if (c) __syncthreads();
#pragma unroll
    for (int k = 0; k < 4; ++k) {
      int slot = tid + k * 512;
      int n = slot >> 5, d4 = slot & 31;
      *(float4*)(wbuf + n * WB_STR + d4 * 4) =
          *(const float4*)(w_t + (size_t)(c * 64 + n) * DD + d4 * 4);
    }
    if (c == 0) {
#pragma unroll
      for (int k = 0; k < 8; ++k) {
        int slot = tid + k * 512;
        int n = slot >> 4, t4 = slot & 15;
        *(float4*)(fs + n * FS_STR + t4 * 4) =
            *(const float4*)(feat + ((size_t)(b * NN + n)) * TT + t0 + t4 * 4);
      }
    }
    __syncthreads();

    const float* fp = fs + (c * 64) * FS_STR + tt * 4;
    const float* wp = wbuf + td * 4;
#pragma unroll 4
    for (int n = 0; n < 64; ++n) {
      float4 f = *(const float4*)(fp + n * FS_STR);
      float4 wv = *(const float4*)(wp + n * WB_STR);
      float fa[4] = {f.x, f.y, f.z, f.w};
#pragma unroll
      for (int i = 0; i < 4; ++i) {
        acc[i][0] += fa[i] * wv.x;
        acc[i][1] += fa[i] * wv.y;
        acc[i][2] += fa[i] * wv.z;
        acc[i][3] += fa[i] * wv.w;
      }
    }
  }

  float s[4];
#pragma unroll
  for (int i = 0; i < 4; ++i)
    s[i] = acc[i][0] * acc[i][0] + acc[i][1] * acc[i][1] +
           acc[i][2] * acc[i][2] + acc[i][3] * acc[i][3];
#pragma unroll
  for (int m = 1; m < 32; m <<= 1) {
#pragma unroll
    for (int i = 0; i < 4; ++i) s[i] += __shfl_xor(s[i], m, 64);
  }
#pragma unroll
  for (int i = 0; i < 4; ++i) {
    float inv = 1.0f / fmaxf(sqrtf(s[i]), 1e-12f);
    float4 o;
    o.x = acc[i][0] * inv; o.y = acc[i][1] * inv;
    o.z = acc[i][2] * inv; o.w = acc[i][3] * inv;
    *(float4*)(projn + ((size_t)(b * TT + t0 + tt * 4 + i)) * DD + td * 4) = o;
  }
}

// ---------------- kernel 4: band+FC v3 — f16 LDS window, own row from GLOBAL ----------------
// Own row loaded from projn (L2-hit) and converted to f16 in registers: the
// compiler cannot rematerialize it from LDS (R10's failure mode). Broadcast
// side reads f16 LDS: 16 b128/s-row (was 32). 70.5 KB LDS -> 2 blocks/CU.
__global__ __launch_bounds__(512, 4) void band_fc_kernel(
    const float* __restrict__ projn, const float* __restrict__ wfc_t,
    const float* __restrict__ b_fc, float* __restrict__ out) {
  extern __shared__ unsigned int smemF[];
  unsigned int* p16 = smemF;                       // [ROWS][68] u32 (f16 pairs)
  float* band = (float*)(smemF + ROWS * P16W);     // [64][101]
  int b = blockIdx.x >> 6;
  int t0 = (blockIdx.x & 63) << 6;
  int tid = threadIdx.x;
  int w = tid >> 6, tt = tid & 63;

  // stage P window as f16 (zero-fill OOB); 2-way store aliasing = free
  const float4* pg = (const float4*)projn;
  for (int i = tid; i < ROWS * 32; i += 512) {
    int r = i >> 5, c = i & 31;
    int t = t0 + r - PADK;
    unsigned int w0 = 0, w1 = 0;
    if (t >= 0 && t < TT) {
      float4 v = pg[(((size_t)b * TT + t) << 5) + c];
      w0 = pk16(v.x, v.y);
      w1 = pk16(v.z, v.w);
    }
    p16[r * P16W + c * 2] = w0;
    p16[r * P16W + c * 2 + 1] = w1;
  }

  // own row: 32 float4 from global (L2-hit), converted to 64 half2 regs
  half2v own2[64];
  {
    const float4* orow = (const float4*)(projn + ((size_t)(b * TT + t0 + tt)) * DD);
#pragma unroll
    for (int c = 0; c < 32; ++c) {
      float4 v = orow[c];
      own2[2 * c]     = h2(pk16(v.x, v.y));
      own2[2 * c + 1] = h2(pk16(v.z, v.w));
    }
  }
  __syncthreads();

  int s0 = w * 21;
  int sEnd = (s0 + 21 < ROWS) ? (s0 + 21) : ROWS;
  for (int s = s0; s < sEnd; ++s) {
    const vuint4* ps = (const vuint4*)(p16 + s * P16W);
    float a0 = 0.f, a1 = 0.f, a2 = 0.f, a3 = 0.f;
#pragma unroll
    for (int c = 0; c < 16; ++c) {
      vuint4 v = ps[c];                // wave-uniform -> LDS broadcast
      a0 = fdot2f(own2[c * 4 + 0], h2(v.x), a0);
      a1 = fdot2f(own2[c * 4 + 1], h2(v.y), a1);
      a2 = fdot2f(own2[c * 4 + 2], h2(v.z), a2);
      a3 = fdot2f(own2[c * 4 + 3], h2(v.w), a3);
    }
    int j = s - tt;
    if (j >= 0 && j < LK) band[tt * LK + j] = (a0 + a1) + (a2 + a3);
  }
  __syncthreads();

  // FC + ReLU (f32)
  int o0u = __builtin_amdgcn_readfirstlane((tid >> 6) * 16);
  float acc[16];
  const float4* bf4 = (const float4*)(b_fc + o0u);
#pragma unroll
  for (int k = 0; k < 4; ++k) {
    float4 bv = bf4[k];
    acc[4 * k + 0] = bv.x; acc[4 * k + 1] = bv.y;
    acc[4 * k + 2] = bv.z; acc[4 * k + 3] = bv.w;
  }
#pragma unroll 2
  for (int j = 0; j < LK; ++j) {
    float bv = band[tt * LK + j];                 // gcd(101,32)=1: conflict-free
    const float4* wr = (const float4*)(wfc_t + j * OD + o0u);  // uniform
#pragma unroll
    for (int k = 0; k < 4; ++k) {
      float4 wv = wr[k];
      acc[4 * k + 0] += wv.x * bv;
      acc[4 * k + 1] += wv.y * bv;
      acc[4 * k + 2] += wv.z * bv;
      acc[4 * k + 3] += wv.w * bv;
    }
  }
  float4* og = (float4*)(out + ((size_t)(b * TT + t0 + tt)) * OD + o0u);
#pragma unroll
  for (int k = 0; k < 4; ++k) {
    float4 o;
    o.x = fmaxf(acc[4 * k + 0], 0.f);
    o.y = fmaxf(acc[4 * k + 1], 0.f);
    o.z = fmaxf(acc[4 * k + 2], 0.f);
    o.w = fmaxf(acc[4 * k + 3], 0.f);
    og[k] = o;
  }
}

extern "C" void kernel_launch(void* const* d_in, const int* in_sizes, int n_in,
                              void* d_out, int out_size, void* d_ws, size_t ws_size,
                              hipStream_t stream) {
  const float* x      = (const float*)d_in[0];
  const float* w_proj = (const float*)d_in[1];
  const float* w_fc   = (const float*)d_in[2];
  const float* b_fc   = (const float*)d_in[3];
  float* out = (float*)d_out;

  char* ws = (char*)d_ws;
  float* feat  = (float*)ws;                                    // B*N*T f32  = 16,777,216 B
  float* projn = (float*)(ws + 16777216);                       // B*T*D f32  =  8,388,608 B
  float* w_t   = (float*)(ws + 16777216 + 8388608);             // N*D f32    =    131,072 B
  float* wfc_t = (float*)(ws + 16777216 + 8388608 + 131072);    // LK*OD f32  =     51,712 B

  size_t smP = (size_t)(NN * FS_STR + 64 * WB_STR) * sizeof(float);                 // 103,424 B
  size_t smF = (size_t)ROWS * P16W * sizeof(int) + (size_t)64 * LK * sizeof(float); //  70,464 B
  (void)hipFuncSetAttribute((const void*)proj_kernel,
                      hipFuncAttributeMaxDynamicSharedMemorySize, (int)smP);
  (void)hipFuncSetAttribute((const void*)band_fc_kernel,
                      hipFuncAttributeMaxDynamicSharedMemorySize, (int)smF);

  transpose_w_kernel<<<64, 256, 0, stream>>>(w_proj, w_fc, w_t, wfc_t);
  pool_kernel<<<(BB * NN * TT) / 512, 256, 0, stream>>>(x, feat);
  proj_kernel<<<BB * (TT / 64), 512, smP, stream>>>(feat, w_t, projn);
  band_fc_kernel<<<BB * (TT / 64), 512, smF, stream>>>(projn, wfc_t, b_fc, out);
}

// Round 13
// 208.093 us; speedup vs baseline: 1.1534x; 1.1534x over previous
//
#include <hip/hip_runtime.h>

#define BB   4
#define NN   256
#define TT   4096
#define DD   128      // SIM_DIM
#define LK   101      // LOOKUP
#define PADK 50
#define OD   128      // OUT_DIM
#define ROWS 164      // 64 + LK - 1 rows of halo'd proj window
#define RSTR 33       // band: row stride in float4 units (132 floats ≡ 4 mod 32 words: even bank spread)
#define FS_STR 68     // proj fs row stride (64 t + 4 pad)
#define WB_STR 132    // proj wbuf row stride (128 d + 4 pad)

typedef float vfloat4 __attribute__((ext_vector_type(4)));

// ---------------- kernel 1: one-time weight transposes ----------------
__global__ __launch_bounds__(256) void transpose_w_kernel(
    const float* __restrict__ w_proj, const float* __restrict__ w_fc,
    float* __restrict__ w_t, float* __restrict__ wfc_t) {
  int idx = blockIdx.x * 256 + threadIdx.x;
  int stride = gridDim.x * 256;
  for (int i = idx; i < DD * NN; i += stride) {
    int d = i / NN, n = i - d * NN;
    w_t[n * DD + d] = w_proj[i];
  }
  for (int i = idx; i < OD * LK; i += stride) {
    int o = i / LK, j = i - o * LK;
    wfc_t[j * OD + o] = w_fc[i];
  }
}

// ---------------- kernel 2: spatial mean-pool v2 (R11 exact, NT restored) ----------------
__global__ __launch_bounds__(256) void pool_kernel(
    const float* __restrict__ x, float* __restrict__ feat) {
  __shared__ float part[512 * 13];   // 26.6 KB
  int tid = threadIdx.x;
  const vfloat4* x4 = (const vfloat4*)x + (size_t)blockIdx.x * 6144;

  vfloat4 v[24];
#pragma unroll
  for (int k = 0; k < 24; ++k)
    v[k] = __builtin_nontemporal_load(&x4[tid + 256 * k]);

#pragma unroll
  for (int k = 0; k < 24; ++k) {
    int j = tid + 256 * k;
    int r = j / 12, i = j - r * 12;
    part[r * 13 + i] = (v[k].x + v[k].y) + (v[k].z + v[k].w);
  }
  __syncthreads();

  float* fo = feat + (size_t)blockIdx.x * 512;
#pragma unroll
  for (int q = 0; q < 2; ++q) {
    int o = tid + q * 256;
    const float* pp = part + o * 13;
    float a0 = 0.f, a1 = 0.f;
#pragma unroll
    for (int i = 0; i < 6; ++i) { a0 += pp[i]; a1 += pp[6 + i]; }
    fo[o] = (a0 + a1) * (1.0f / 48.0f);
  }
}

// ---------------- kernel 3: projection + L2 normalize (R8 exact) ----------------
__global__ __launch_bounds__(512, 1) void proj_kernel(
    const float* __restrict__ feat, const float* __restrict__ w_t,
    float* __restrict__ projn) {
  extern __shared__ float smemP[];
  float* fs   = smemP;               // [256 n][68]
  float* wbuf = smemP + NN * FS_STR; // [64 n][132]
  int b = blockIdx.x >> 6;
  int t0 = (blockIdx.x & 63) << 6;
  int tid = threadIdx.x;
  int td = tid & 31, tt = tid >> 5;

  float acc[4][4];
#pragma unroll
  for (int i = 0; i < 4; ++i)
#pragma unroll
    for (int j = 0; j < 4; ++j) acc[i][j] = 0.f;

  for (int c = 0; c < 4; ++c) {
    if (c) __syncthreads();
#pragma unroll
    for (int k = 0; k < 4; ++k) {
      int slot = tid + k * 512;
      int n = slot >> 5, d4 = slot & 31;
      *(float4*)(wbuf + n * WB_STR + d4 * 4) =
          *(const float4*)(w_t + (size_t)(c * 64 + n) * DD + d4 * 4);
    }
    if (c == 0) {
#pragma unroll
      for (int k = 0; k < 8; ++k) {
        int slot = tid + k * 512;
        int n = slot >> 4, t4 = slot & 15;
        *(float4*)(fs + n * FS_STR + t4 * 4) =
            *(const float4*)(feat + ((size_t)(b * NN + n)) * TT + t0 + t4 * 4);
      }
    }
    __syncthreads();

    const float* fp = fs + (c * 64) * FS_STR + tt * 4;
    const float* wp = wbuf + td * 4;
#pragma unroll 4
    for (int n = 0; n < 64; ++n) {
      float4 f = *(const float4*)(fp + n * FS_STR);
      float4 wv = *(const float4*)(wp + n * WB_STR);
      float fa[4] = {f.x, f.y, f.z, f.w};
#pragma unroll
      for (int i = 0; i < 4; ++i) {
        acc[i][0] += fa[i] * wv.x;
        acc[i][1] += fa[i] * wv.y;
        acc[i][2] += fa[i] * wv.z;
        acc[i][3] += fa[i] * wv.w;
      }
    }
  }

  float s[4];
#pragma unroll
  for (int i = 0; i < 4; ++i)
    s[i] = acc[i][0] * acc[i][0] + acc[i][1] * acc[i][1] +
           acc[i][2] * acc[i][2] + acc[i][3] * acc[i][3];
#pragma unroll
  for (int m = 1; m < 32; m <<= 1) {
#pragma unroll
    for (int i = 0; i < 4; ++i) s[i] += __shfl_xor(s[i], m, 64);
  }
#pragma unroll
  for (int i = 0; i < 4; ++i) {
    float inv = 1.0f / fmaxf(sqrtf(s[i]), 1e-12f);
    float4 o;
    o.x = acc[i][0] * inv; o.y = acc[i][1] * inv;
    o.z = acc[i][2] * inv; o.w = acc[i][3] * inv;
    *(float4*)(projn + ((size_t)(b * TT + t0 + tt * 4 + i)) * DD + td * 4) = o;
  }
}

// ---------------- kernel 4: band+FC v4 — f32, j-loop (full-BW distinct LDS reads) ----------------
// Phase 1 iterates j (not s): lane tt reads row tt+j per-lane DISTINCT
// (stride 132 words ≡ 4 mod 32: 8 words/bank, conflict-even) — 1024 B per
// ~12-cyc b128 instead of a 16 B broadcast. 3232 LDS instr/block (was 5248).
__global__ __launch_bounds__(512, 1) void band_fc_kernel(
    const float* __restrict__ projn, const float* __restrict__ wfc_t,
    const float* __restrict__ b_fc, float* __restrict__ out) {
  extern __shared__ float4 smemC[];
  float4* p4 = smemC;                            // [ROWS][RSTR]
  float* band = (float*)(smemC + ROWS * RSTR);   // [64][101]
  int b = blockIdx.x >> 6;
  int t0 = (blockIdx.x & 63) << 6;
  int tid = threadIdx.x;

  const float4* pg = (const float4*)projn;
  for (int i = tid; i < ROWS * 32; i += 512) {
    int r = i >> 5, c = i & 31;
    int t = t0 + r - PADK;
    float4 v = make_float4(0.f, 0.f, 0.f, 0.f);
    if (t >= 0 && t < TT) v = pg[(((size_t)b * TT + t) << 5) + c];
    p4[r * RSTR + c] = v;
  }
  __syncthreads();

  int w = tid >> 6, tt = tid & 63;

  float4 own[32];
#pragma unroll
  for (int c = 0; c < 32; ++c) own[c] = p4[(tt + PADK) * RSTR + c];

  // wave w handles j in [13w, min(101, 13w+13))
  int j0 = w * 13;
  int jEnd = (j0 + 13 < LK) ? (j0 + 13) : LK;
  for (int j = j0; j < jEnd; ++j) {
    const float4* pr = p4 + (tt + j) * RSTR;     // per-lane distinct rows
    float a0 = 0.f, a1 = 0.f, a2 = 0.f, a3 = 0.f;
#pragma unroll
    for (int c = 0; c < 32; ++c) {
      float4 ov = pr[c];
      a0 += own[c].x * ov.x;
      a1 += own[c].y * ov.y;
      a2 += own[c].z * ov.z;
      a3 += own[c].w * ov.w;
    }
    band[tt * LK + j] = (a0 + a1) + (a2 + a3);   // stride 101 ≡ 5 mod 32: conflict-free
  }
  __syncthreads();

  int o0u = __builtin_amdgcn_readfirstlane((tid >> 6) * 16);
  float acc[16];
  const float4* bf4 = (const float4*)(b_fc + o0u);
#pragma unroll
  for (int k = 0; k < 4; ++k) {
    float4 bv = bf4[k];
    acc[4 * k + 0] = bv.x; acc[4 * k + 1] = bv.y;
    acc[4 * k + 2] = bv.z; acc[4 * k + 3] = bv.w;
  }
#pragma unroll 2
  for (int j = 0; j < LK; ++j) {
    float bv = band[tt * LK + j];                 // gcd(101,32)=1: conflict-free
    const float4* wr = (const float4*)(wfc_t + j * OD + o0u);  // uniform
#pragma unroll
    for (int k = 0; k < 4; ++k) {
      float4 wv = wr[k];
      acc[4 * k + 0] += wv.x * bv;
      acc[4 * k + 1] += wv.y * bv;
      acc[4 * k + 2] += wv.z * bv;
      acc[4 * k + 3] += wv.w * bv;
    }
  }
  float4* og = (float4*)(out + ((size_t)(b * TT + t0 + tt)) * OD + o0u);
#pragma unroll
  for (int k = 0; k < 4; ++k) {
    float4 o;
    o.x = fmaxf(acc[4 * k + 0], 0.f);
    o.y = fmaxf(acc[4 * k + 1], 0.f);
    o.z = fmaxf(acc[4 * k + 2], 0.f);
    o.w = fmaxf(acc[4 * k + 3], 0.f);
    og[k] = o;
  }
}

extern "C" void kernel_launch(void* const* d_in, const int* in_sizes, int n_in,
                              void* d_out, int out_size, void* d_ws, size_t ws_size,
                              hipStream_t stream) {
  const float* x      = (const float*)d_in[0];
  const float* w_proj = (const float*)d_in[1];
  const float* w_fc   = (const float*)d_in[2];
  const float* b_fc   = (const float*)d_in[3];
  float* out = (float*)d_out;

  char* ws = (char*)d_ws;
  float* feat  = (float*)ws;                                    // B*N*T f32  = 16,777,216 B
  float* projn = (float*)(ws + 16777216);                       // B*T*D f32  =  8,388,608 B
  float* w_t   = (float*)(ws + 16777216 + 8388608);             // N*D f32    =    131,072 B
  float* wfc_t = (float*)(ws + 16777216 + 8388608 + 131072);    // LK*OD f32  =     51,712 B

  size_t smP = (size_t)(NN * FS_STR + 64 * WB_STR) * sizeof(float);                    // 103,424 B
  size_t smC = (size_t)ROWS * RSTR * sizeof(float4) + (size_t)64 * LK * sizeof(float); // 112,448 B
  (void)hipFuncSetAttribute((const void*)proj_kernel,
                      hipFuncAttributeMaxDynamicSharedMemorySize, (int)smP);
  (void)hipFuncSetAttribute((const void*)band_fc_kernel,
                      hipFuncAttributeMaxDynamicSharedMemorySize, (int)smC);

  transpose_w_kernel<<<64, 256, 0, stream>>>(w_proj, w_fc, w_t, wfc_t);
  pool_kernel<<<(BB * NN * TT) / 512, 256, 0, stream>>>(x, feat);
  proj_kernel<<<BB * (TT / 64), 512, smP, stream>>>(feat, w_t, projn);
  band_fc_kernel<<<BB * (TT / 64), 512, smC, stream>>>(projn, wfc_t, b_fc, out);
}

// Round 14
// 205.115 us; speedup vs baseline: 1.1701x; 1.0145x over previous
//
#include <hip/hip_runtime.h>

#define BB   4
#define NN   256
#define TT   4096
#define DD   128      // SIM_DIM
#define LK   101      // LOOKUP
#define PADK 50
#define OD   128      // OUT_DIM
#define ROWS 164      // 64 + LK - 1 rows of halo'd proj window
#define RSTR 33       // band: row stride in float4 units (132 floats ≡ 4 mod 32 words)
#define FS_STR 68     // proj fs row stride (64 t + 4 pad)
#define WB_STR 132    // proj wbuf row stride (128 d + 4 pad)

typedef float vfloat4 __attribute__((ext_vector_type(4)));

// -------- kernel 1: spatial mean-pool v4 (12-deep x2 batches, occupancy 4->6 blk/CU) --------
// + folded weight transposes on blocks 0..63 (first-scheduled: zero tail cost).
__global__ __launch_bounds__(256) void pool_kernel(
    const float* __restrict__ x, float* __restrict__ feat,
    const float* __restrict__ w_proj, const float* __restrict__ w_fc,
    float* __restrict__ w_t, float* __restrict__ wfc_t) {
  __shared__ float part[512 * 13];   // 26.6 KB -> 6 blocks/CU (LDS cap)
  int tid = threadIdx.x;
  const vfloat4* x4 = (const vfloat4*)x + (size_t)blockIdx.x * 6144;

  vfloat4 v[12];                     // ~70 VGPR total: 6 waves/SIMD feasible
#pragma unroll
  for (int h = 0; h < 2; ++h) {
#pragma unroll
    for (int k = 0; k < 12; ++k)
      v[k] = __builtin_nontemporal_load(&x4[tid + 256 * (h * 12 + k)]);
#pragma unroll
    for (int k = 0; k < 12; ++k) {
      int j = tid + 256 * (h * 12 + k);
      int r = j / 12, i = j - r * 12;
      part[r * 13 + i] = (v[k].x + v[k].y) + (v[k].z + v[k].w);
    }
  }
  __syncthreads();

  float* fo = feat + (size_t)blockIdx.x * 512;
#pragma unroll
  for (int q = 0; q < 2; ++q) {
    int o = tid + q * 256;
    const float* pp = part + o * 13;
    float a0 = 0.f, a1 = 0.f;
#pragma unroll
    for (int i = 0; i < 6; ++i) { a0 += pp[i]; a1 += pp[6 + i]; }
    fo[o] = (a0 + a1) * (1.0f / 48.0f);
  }

  // folded transposes: w_proj[128][256] -> w_t[256][128]; w_fc[128][101] -> wfc_t[101][128]
  if (blockIdx.x < 64) {
    int idx = blockIdx.x * 256 + tid;            // 0..16383
#pragma unroll
    for (int r = 0; r < 2; ++r) {
      int i = idx + r * 16384;                   // covers 32768 = DD*NN
      int d = i >> 8, n = i & 255;
      w_t[n * DD + d] = w_proj[i];
    }
    if (idx < OD * LK) {
      int o = idx / LK, j = idx - o * LK;
      wfc_t[j * OD + o] = w_fc[idx];
    }
  }
}

// ---------------- kernel 2: projection + L2 normalize (R8 exact, measured 21.3 us) ----------------
__global__ __launch_bounds__(512, 1) void proj_kernel(
    const float* __restrict__ feat, const float* __restrict__ w_t,
    float* __restrict__ projn) {
  extern __shared__ float smemP[];
  float* fs   = smemP;               // [256 n][68]
  float* wbuf = smemP + NN * FS_STR; // [64 n][132]
  int b = blockIdx.x >> 6;
  int t0 = (blockIdx.x & 63) << 6;
  int tid = threadIdx.x;
  int td = tid & 31, tt = tid >> 5;

  float acc[4][4];
#pragma unroll
  for (int i = 0; i < 4; ++i)
#pragma unroll
    for (int j = 0; j < 4; ++j) acc[i][j] = 0.f;

  for (int c = 0; c < 4; ++c) {
    if (c) __syncthreads();
#pragma unroll
    for (int k = 0; k < 4; ++k) {
      int slot = tid + k * 512;
      int n = slot >> 5, d4 = slot & 31;
      *(float4*)(wbuf + n * WB_STR + d4 * 4) =
          *(const float4*)(w_t + (size_t)(c * 64 + n) * DD + d4 * 4);
    }
    if (c == 0) {
#pragma unroll
      for (int k = 0; k < 8; ++k) {
        int slot = tid + k * 512;
        int n = slot >> 4, t4 = slot & 15;
        *(float4*)(fs + n * FS_STR + t4 * 4) =
            *(const float4*)(feat + ((size_t)(b * NN + n)) * TT + t0 + t4 * 4);
      }
    }
    __syncthreads();

    const float* fp = fs + (c * 64) * FS_STR + tt * 4;
    const float* wp = wbuf + td * 4;
#pragma unroll 4
    for (int n = 0; n < 64; ++n) {
      float4 f = *(const float4*)(fp + n * FS_STR);
      float4 wv = *(const float4*)(wp + n * WB_STR);
      float fa[4] = {f.x, f.y, f.z, f.w};
#pragma unroll
      for (int i = 0; i < 4; ++i) {
        acc[i][0] += fa[i] * wv.x;
        acc[i][1] += fa[i] * wv.y;
        acc[i][2] += fa[i] * wv.z;
        acc[i][3] += fa[i] * wv.w;
      }
    }
  }

  float s[4];
#pragma unroll
  for (int i = 0; i < 4; ++i)
    s[i] = acc[i][0] * acc[i][0] + acc[i][1] * acc[i][1] +
           acc[i][2] * acc[i][2] + acc[i][3] * acc[i][3];
#pragma unroll
  for (int m = 1; m < 32; m <<= 1) {
#pragma unroll
    for (int i = 0; i < 4; ++i) s[i] += __shfl_xor(s[i], m, 64);
  }
#pragma unroll
  for (int i = 0; i < 4; ++i) {
    float inv = 1.0f / fmaxf(sqrtf(s[i]), 1e-12f);
    float4 o;
    o.x = acc[i][0] * inv; o.y = acc[i][1] * inv;
    o.z = acc[i][2] * inv; o.w = acc[i][3] * inv;
    *(float4*)(projn + ((size_t)(b * TT + t0 + tt * 4 + i)) * DD + td * 4) = o;
  }
}

// ---------------- kernel 3: band+FC v4 (R13 exact — j-loop, distinct-row LDS reads) ----------------
__global__ __launch_bounds__(512, 1) void band_fc_kernel(
    const float* __restrict__ projn, const float* __restrict__ wfc_t,
    const float* __restrict__ b_fc, float* __restrict__ out) {
  extern __shared__ float4 smemC[];
  float4* p4 = smemC;                            // [ROWS][RSTR]
  float* band = (float*)(smemC + ROWS * RSTR);   // [64][101]
  int b = blockIdx.x >> 6;
  int t0 = (blockIdx.x & 63) << 6;
  int tid = threadIdx.x;

  const float4* pg = (const float4*)projn;
  for (int i = tid; i < ROWS * 32; i += 512) {
    int r = i >> 5, c = i & 31;
    int t = t0 + r - PADK;
    float4 v = make_float4(0.f, 0.f, 0.f, 0.f);
    if (t >= 0 && t < TT) v = pg[(((size_t)b * TT + t) << 5) + c];
    p4[r * RSTR + c] = v;
  }
  __syncthreads();

  int w = tid >> 6, tt = tid & 63;

  float4 own[32];
#pragma unroll
  for (int c = 0; c < 32; ++c) own[c] = p4[(tt + PADK) * RSTR + c];

  int j0 = w * 13;
  int jEnd = (j0 + 13 < LK) ? (j0 + 13) : LK;
  for (int j = j0; j < jEnd; ++j) {
    const float4* pr = p4 + (tt + j) * RSTR;     // per-lane distinct rows
    float a0 = 0.f, a1 = 0.f, a2 = 0.f, a3 = 0.f;
#pragma unroll
    for (int c = 0; c < 32; ++c) {
      float4 ov = pr[c];
      a0 += own[c].x * ov.x;
      a1 += own[c].y * ov.y;
      a2 += own[c].z * ov.z;
      a3 += own[c].w * ov.w;
    }
    band[tt * LK + j] = (a0 + a1) + (a2 + a3);
  }
  __syncthreads();

  int o0u = __builtin_amdgcn_readfirstlane((tid >> 6) * 16);
  float acc[16];
  const float4* bf4 = (const float4*)(b_fc + o0u);
#pragma unroll
  for (int k = 0; k < 4; ++k) {
    float4 bv = bf4[k];
    acc[4 * k + 0] = bv.x; acc[4 * k + 1] = bv.y;
    acc[4 * k + 2] = bv.z; acc[4 * k + 3] = bv.w;
  }
#pragma unroll 2
  for (int j = 0; j < LK; ++j) {
    float bv = band[tt * LK + j];                 // gcd(101,32)=1: conflict-free
    const float4* wr = (const float4*)(wfc_t + j * OD + o0u);  // uniform -> scalar loads
#pragma unroll
    for (int k = 0; k < 4; ++k) {
      float4 wv = wr[k];
      acc[4 * k + 0] += wv.x * bv;
      acc[4 * k + 1] += wv.y * bv;
      acc[4 * k + 2] += wv.z * bv;
      acc[4 * k + 3] += wv.w * bv;
    }
  }
  float4* og = (float4*)(out + ((size_t)(b * TT + t0 + tt)) * OD + o0u);
#pragma unroll
  for (int k = 0; k < 4; ++k) {
    float4 o;
    o.x = fmaxf(acc[4 * k + 0], 0.f);
    o.y = fmaxf(acc[4 * k + 1], 0.f);
    o.z = fmaxf(acc[4 * k + 2], 0.f);
    o.w = fmaxf(acc[4 * k + 3], 0.f);
    og[k] = o;
  }
}

extern "C" void kernel_launch(void* const* d_in, const int* in_sizes, int n_in,
                              void* d_out, int out_size, void* d_ws, size_t ws_size,
                              hipStream_t stream) {
  const float* x      = (const float*)d_in[0];
  const float* w_proj = (const float*)d_in[1];
  const float* w_fc   = (const float*)d_in[2];
  const float* b_fc   = (const float*)d_in[3];
  float* out = (float*)d_out;

  char* ws = (char*)d_ws;
  float* feat  = (float*)ws;                                    // B*N*T f32  = 16,777,216 B
  float* projn = (float*)(ws + 16777216);                       // B*T*D f32  =  8,388,608 B
  float* w_t   = (float*)(ws + 16777216 + 8388608);             // N*D f32    =    131,072 B
  float* wfc_t = (float*)(ws + 16777216 + 8388608 + 131072);    // LK*OD f32  =     51,712 B

  size_t smP = (size_t)(NN * FS_STR + 64 * WB_STR) * sizeof(float);                    // 103,424 B
  size_t smC = (size_t)ROWS * RSTR * sizeof(float4) + (size_t)64 * LK * sizeof(float); // 112,448 B
  (void)hipFuncSetAttribute((const void*)proj_kernel,
                      hipFuncAttributeMaxDynamicSharedMemorySize, (int)smP);
  (void)hipFuncSetAttribute((const void*)band_fc_kernel,
                      hipFuncAttributeMaxDynamicSharedMemorySize, (int)smC);

  pool_kernel<<<(BB * NN * TT) / 512, 256, 0, stream>>>(x, feat, w_proj, w_fc, w_t, wfc_t);
  proj_kernel<<<BB * (TT / 64), 512, smP, stream>>>(feat, w_t, projn);
  band_fc_kernel<<<BB * (TT / 64), 512, smC, stream>>>(projn, wfc_t, b_fc, out);
}